// Round 1
// baseline (286.844 us; speedup 1.0000x reference)
//
#include <hip/hip_runtime.h>
#include <math.h>

// Problem constants (static per reference)
#define B_    256
#define N_    400
#define D_    256
#define EPG_  12800          // N*DEG edges per graph (block-diagonal, contiguous)
#define E_    3276800        // B*EPG
#define NT_   102400         // B*N
#define K_    200            // ceil(0.5*N)
#define NKC_  200            // N-K

// Output flat offsets (float32 elements, in return order).
// O_FDIS..O_FCOM regions are contiguous, so concatenated output row
// r in [0, B*N) lives at out + r*D  (r < B*K => dis, else com).
#define O_FDIS 0
#define O_FCOM 13107200      // + B*K*D
#define O_PERM 26214400      // + B*NKC*D
#define O_PCOM 26265600      // + B*K
#define O_SOFT 26316800      // + B*NKC
#define O_EDIS 26419200      // + NT
#define O_ECOM 29696000      // + E

#define NEG_INF (-3.402823466e38f)

// Raw dot products for ALL rows: hraw[n] = dot(feat[n], W). Wave per 4 rows.
// Pure ~105 MB stream. Grid MUST be NT_/16 blocks (16 rows per 256-thr block).
__global__ __launch_bounds__(256) void k_h(const float* __restrict__ feat,
                                           const float* __restrict__ W,
                                           float* __restrict__ hraw) {
    const int gw   = (blockIdx.x * 256 + threadIdx.x) >> 6;
    const int lane = threadIdx.x & 63;
    const float4 w4 = ((const float4*)W)[lane];
    const int r0 = gw * 4;
    const float4* fb = (const float4*)feat;
    float4 a0 = fb[(size_t)(r0    ) * 64 + lane];
    float4 a1 = fb[(size_t)(r0 + 1) * 64 + lane];
    float4 a2 = fb[(size_t)(r0 + 2) * 64 + lane];
    float4 a3 = fb[(size_t)(r0 + 3) * 64 + lane];
    float d0 = a0.x*w4.x + a0.y*w4.y + a0.z*w4.z + a0.w*w4.w;
    float d1 = a1.x*w4.x + a1.y*w4.y + a1.z*w4.z + a1.w*w4.w;
    float d2 = a2.x*w4.x + a2.y*w4.y + a2.z*w4.z + a2.w*w4.w;
    float d3 = a3.x*w4.x + a3.y*w4.y + a3.z*w4.z + a3.w*w4.w;
    #pragma unroll
    for (int off = 32; off > 0; off >>= 1) {
        d0 += __shfl_down(d0, off, 64);
        d1 += __shfl_down(d1, off, 64);
        d2 += __shfl_down(d2, off, 64);
        d3 += __shfl_down(d3, off, 64);
    }
    if (lane == 0) {
        hraw[r0    ] = d0;
        hraw[r0 + 1] = d1;
        hraw[r0 + 2] = d2;
        hraw[r0 + 3] = d3;
    }
}

// One block per graph. Fuses: degree histograms (LDS), normed scatter-sum,
// score, softmax partial, rank-based top-k (== jax.lax.top_k order incl.
// tie-break by lower index), complement positions, and edge-mask writes.
// Edges are fetched from HBM once; passes 2/3 re-read from L2 (102 KB/graph).
// ~6 barriers total (vs ~80 for bitonic sort + scan).
__global__ __launch_bounds__(1024) void k_fused(const int* __restrict__ src,
                                                const int* __restrict__ dst,
                                                const float* __restrict__ hraw,
                                                const float* __restrict__ bp,
                                                float* __restrict__ score,
                                                float* __restrict__ pm,
                                                float* __restrict__ ps,
                                                int* __restrict__ orow,
                                                float* __restrict__ out) {
    __shared__ float hl[N_], scl[N_];
    __shared__ int   ho[N_], hi[N_], smask[N_];
    const int g = blockIdx.x, tid = threadIdx.x;
    const int nbase = g * N_, ebase = g * EPG_;
    const int wave = tid >> 6, lane = tid & 63;

    // Issue the (tiny) hraw read early; it completes under the edge pass.
    float hr = 0.0f;
    if (tid < N_) hr = hraw[nbase + tid];

    if (tid < N_) { ho[tid] = 0; hi[tid] = 0; scl[tid] = 0.0f; }
    __syncthreads();

    // Pass 1: degree histograms (12800 LDS int atomics over 400 slots)
    const int4* s4 = (const int4*)(src + ebase);
    const int4* d4 = (const int4*)(dst + ebase);
    for (int i = tid; i < EPG_ / 4; i += 1024) {
        int4 s = s4[i]; int4 d = d4[i];
        atomicAdd(&ho[s.x - nbase], 1);
        atomicAdd(&ho[s.y - nbase], 1);
        atomicAdd(&ho[s.z - nbase], 1);
        atomicAdd(&ho[s.w - nbase], 1);
        atomicAdd(&hi[d.x - nbase], 1);
        atomicAdd(&hi[d.y - nbase], 1);
        atomicAdd(&hi[d.z - nbase], 1);
        atomicAdd(&hi[d.w - nbase], 1);
    }
    __syncthreads();

    if (tid < N_)
        hl[tid] = hr * (1.0f / sqrtf(fmaxf((float)ho[tid], 1.0f)));
    __syncthreads();

    // Pass 2: normed scatter-sum (edges are L2-hot now)
    for (int i = tid; i < EPG_ / 4; i += 1024) {
        int4 s = s4[i]; int4 d = d4[i];
        atomicAdd(&scl[d.x - nbase], hl[s.x - nbase]);
        atomicAdd(&scl[d.y - nbase], hl[s.y - nbase]);
        atomicAdd(&scl[d.z - nbase], hl[s.z - nbase]);
        atomicAdd(&scl[d.w - nbase], hl[s.w - nbase]);
    }
    __syncthreads();

    const float bb = bp[0];
    if (tid < N_) {
        float v = scl[tid] * (1.0f / sqrtf(fmaxf((float)hi[tid], 1.0f))) + bb;
        scl[tid] = v;
        score[nbase + tid] = v;
    }
    __syncthreads();

    // Rank-select top-k (threads 0..N-1; LDS broadcast reads, no barriers).
    // rank_i = #{j : s_j > s_i  or (s_j == s_i and j < i)}  -> selected iff < K,
    // position in top-k list == rank (matches lax.top_k stable descending).
    if (tid < N_) {
        const float v = scl[tid];
        int r = 0;
        for (int j = 0; j < N_; ++j) {
            float u = scl[j];
            r += (u > v) || (u == v && j < tid);
        }
        const int selb = (r < K_) ? 1 : 0;
        smask[tid] = selb;
        if (selb) {
            orow[nbase + tid] = g * K_ + r;                 // dis rows: [0, B*K)
            out[O_PERM + g * K_ + r] = (float)(nbase + tid);
        }
    }
    // Wave 15 (threads 960..1023, idle above) does the softmax partial.
    if (wave == 15) {
        float m = NEG_INF;
        for (int i = lane; i < N_; i += 64) m = fmaxf(m, scl[i]);
        #pragma unroll
        for (int o = 32; o > 0; o >>= 1) m = fmaxf(m, __shfl_xor(m, o, 64));
        float s = 0.0f;
        for (int i = lane; i < N_; i += 64) s += expf(scl[i] - m);
        #pragma unroll
        for (int o = 32; o > 0; o >>= 1) s += __shfl_xor(s, o, 64);
        if (lane == 0) { pm[g] = m; ps[g] = s; }
    }
    __syncthreads();

    // Complement positions: ascending index among unselected.
    if (tid < N_ && !smask[tid]) {
        int pos = 0;
        for (int u = 0; u < tid; ++u) pos += (smask[u] == 0);
        orow[nbase + tid] = B_ * K_ + g * NKC_ + pos;       // com rows: [B*K, B*N)
        out[O_PCOM + g * NKC_ + pos] = (float)(nbase + tid);
    }

    // Pass 3: edge masks straight from LDS smask (edges still L2-hot).
    float4* mdis = (float4*)(out + O_EDIS) + g * (EPG_ / 4);
    float4* mcom = (float4*)(out + O_ECOM) + g * (EPG_ / 4);
    for (int i = tid; i < EPG_ / 4; i += 1024) {
        int4 s = s4[i]; int4 d = d4[i];
        int a0 = smask[s.x - nbase], a1 = smask[s.y - nbase];
        int a2 = smask[s.z - nbase], a3 = smask[s.w - nbase];
        int b0 = smask[d.x - nbase], b1 = smask[d.y - nbase];
        int b2 = smask[d.z - nbase], b3 = smask[d.w - nbase];
        float4 vdis, vcom;
        vdis.x = (a0 & b0) ? 1.0f : 0.0f;  vcom.x = (a0 | b0) ? 0.0f : 1.0f;
        vdis.y = (a1 & b1) ? 1.0f : 0.0f;  vcom.y = (a1 | b1) ? 0.0f : 1.0f;
        vdis.z = (a2 & b2) ? 1.0f : 0.0f;  vcom.z = (a2 | b2) ? 0.0f : 1.0f;
        vdis.w = (a3 & b3) ? 1.0f : 0.0f;  vcom.w = (a3 | b3) ? 0.0f : 1.0f;
        mdis[i] = vdis;
        mcom[i] = vcom;
    }
}

// Combine per-graph (max,sumexp) into global (M,S)
__global__ __launch_bounds__(256) void k_soft_comb(const float* pm, const float* ps, float* red2) {
    __shared__ float rm[256], rs[256];
    int tid = threadIdx.x;
    float m = pm[tid];
    rm[tid] = m; __syncthreads();
    for (int o = 128; o > 0; o >>= 1) { if (tid < o) rm[tid] = fmaxf(rm[tid], rm[tid + o]); __syncthreads(); }
    float M = rm[0]; __syncthreads();
    rs[tid] = ps[tid] * expf(m - M); __syncthreads();
    for (int o = 128; o > 0; o >>= 1) { if (tid < o) rs[tid] += rs[tid + o]; __syncthreads(); }
    if (tid == 0) { red2[0] = M; red2[1] = rs[0]; }
}

// Gated gather with LINEAR feature reads: wave handles 4 consecutive nodes,
// writes each row to out + orow[n]*D (dis/com contiguous). Softmax fused.
// Grid MUST be NT_/16 blocks.
__global__ __launch_bounds__(256) void k_gather(const float* __restrict__ feat,
                                                const float* __restrict__ score,
                                                const int* __restrict__ orow,
                                                const float* __restrict__ red2,
                                                float* __restrict__ out) {
    const int gw   = (blockIdx.x * 256 + threadIdx.x) >> 6;
    const int lane = threadIdx.x & 63;
    const int n0 = gw * 4;
    const float4* fb = (const float4*)feat;
    float4 v0 = fb[(size_t)(n0    ) * 64 + lane];
    float4 v1 = fb[(size_t)(n0 + 1) * 64 + lane];
    float4 v2 = fb[(size_t)(n0 + 2) * 64 + lane];
    float4 v3 = fb[(size_t)(n0 + 3) * 64 + lane];
    float s0 = score[n0], s1 = score[n0 + 1], s2 = score[n0 + 2], s3 = score[n0 + 3];
    int   r0 = orow[n0],  r1 = orow[n0 + 1],  r2 = orow[n0 + 2],  r3 = orow[n0 + 3];
    float t0 = tanhf(s0), t1 = tanhf(s1), t2 = tanhf(s2), t3 = tanhf(s3);
    v0.x *= t0; v0.y *= t0; v0.z *= t0; v0.w *= t0;
    v1.x *= t1; v1.y *= t1; v1.z *= t1; v1.w *= t1;
    v2.x *= t2; v2.y *= t2; v2.z *= t2; v2.w *= t2;
    v3.x *= t3; v3.y *= t3; v3.z *= t3; v3.w *= t3;
    ((float4*)(out + (size_t)r0 * D_))[lane] = v0;
    ((float4*)(out + (size_t)r1 * D_))[lane] = v1;
    ((float4*)(out + (size_t)r2 * D_))[lane] = v2;
    ((float4*)(out + (size_t)r3 * D_))[lane] = v3;
    if (lane == 0) {
        float M = red2[0], S = red2[1];
        out[O_SOFT + n0    ] = expf(s0 - M) / S;
        out[O_SOFT + n0 + 1] = expf(s1 - M) / S;
        out[O_SOFT + n0 + 2] = expf(s2 - M) / S;
        out[O_SOFT + n0 + 3] = expf(s3 - M) / S;
    }
}

extern "C" void kernel_launch(void* const* d_in, const int* in_sizes, int n_in,
                              void* d_out, int out_size, void* d_ws, size_t ws_size,
                              hipStream_t stream) {
    const float* feat = (const float*)d_in[0];
    const float* W    = (const float*)d_in[1];
    const float* bp   = (const float*)d_in[2];
    const int*   src  = (const int*)d_in[3];
    const int*   dst  = (const int*)d_in[4];
    float* out = (float*)d_out;

    char* ws = (char*)d_ws;
    float* hraw  = (float*)(ws + 0);         // NT_ floats
    float* score = (float*)(ws + 409600);    // NT_ floats
    int*   orow  = (int*)  (ws + 819200);    // NT_ ints
    float* pm    = (float*)(ws + 1228800);   // B_ floats
    float* ps    = (float*)(ws + 1229824);   // B_ floats
    float* red2  = (float*)(ws + 1230848);   // 2 floats

    // No memset needed: degree histograms now live in LDS inside k_fused.
    k_h        <<<NT_ / 16, 256, 0, stream>>>(feat, W, hraw);               // 6400 blocks (full coverage)
    k_fused    <<<B_,      1024, 0, stream>>>(src, dst, hraw, bp,
                                              score, pm, ps, orow, out);    // 1 block / graph
    k_soft_comb<<<1,        256, 0, stream>>>(pm, ps, red2);
    k_gather   <<<NT_ / 16, 256, 0, stream>>>(feat, score, orow, red2, out);// 6400 blocks (full coverage)
}

// Round 3
// 285.666 us; speedup vs baseline: 1.0041x; 1.0041x over previous
//
#include <hip/hip_runtime.h>
#include <math.h>

// Problem constants (static per reference)
#define B_    256
#define N_    400
#define D_    256
#define EPG_  12800          // N*DEG edges per graph (block-diagonal, contiguous)
#define E_    3276800        // B*EPG
#define NT_   102400         // B*N
#define K_    200            // ceil(0.5*N)
#define NKC_  200            // N-K

// Output flat offsets (float32 elements, in return order).
// O_FDIS..O_FCOM regions are contiguous, so concatenated output row
// r in [0, B*N) lives at out + r*D  (r < B*K => dis, else com).
#define O_FDIS 0
#define O_FCOM 13107200      // + B*K*D
#define O_PERM 26214400      // + B*NKC*D
#define O_PCOM 26265600      // + B*K
#define O_SOFT 26316800      // + B*NKC
#define O_EDIS 26419200      // + NT
#define O_ECOM 29696000      // + E

#define NEG_INF (-3.402823466e38f)

// Native clang vector type: __builtin_nontemporal_store rejects HIP's
// float4 class but accepts ext_vector_type. Same 16-B layout/alignment.
typedef float nfv4 __attribute__((ext_vector_type(4)));

// Non-temporal float4 store: output is write-once/never-re-read; bypass
// cache retention so `feat` (105 MB) stays resident in L3 for its 2nd read.
static __device__ __forceinline__ void nt_store4(float4* p, float4 v) {
    nfv4 x; x.x = v.x; x.y = v.y; x.z = v.z; x.w = v.w;
    __builtin_nontemporal_store(x, (nfv4*)p);
}

// ---------------------------------------------------------------------------
// Kernel A: one block (1024 thr) per graph. Fuses:
//   phase 0 (overlapped streams): waves 0-11 compute hraw = feat @ W for the
//            graph's 400 rows (410 KB, each row one coalesced 1 KB float4
//            load + wave shuffle-reduce); waves 12-15 build degree
//            histograms from the graph's 12800 edges (102 KB) in LDS.
//   then: normed scatter-sum -> score -> rank-select top-k (matches
//   jax.lax.top_k stable-descending order incl. tie-break by lower index)
//   -> complement positions -> edge masks (edges re-read from L2).
// 6 barriers total. LDS ~8 KB.
// ---------------------------------------------------------------------------
__global__ __launch_bounds__(1024) void k_graph(const float* __restrict__ feat,
                                                const float* __restrict__ W,
                                                const int* __restrict__ src,
                                                const int* __restrict__ dst,
                                                const float* __restrict__ bp,
                                                float* __restrict__ score,
                                                float* __restrict__ pm,
                                                float* __restrict__ ps,
                                                int* __restrict__ orow,
                                                float* __restrict__ out) {
    __shared__ float hl[N_], scl[N_];
    __shared__ int   ho[N_], hi[N_], smask[N_];
    const int g = blockIdx.x, tid = threadIdx.x;
    const int nbase = g * N_, ebase = g * EPG_;
    const int wave = tid >> 6, lane = tid & 63;

    if (tid < N_) { ho[tid] = 0; hi[tid] = 0; scl[tid] = 0.0f; }
    __syncthreads();

    const int4* s4 = (const int4*)(src + ebase);   // 3200 int4
    const int4* d4 = (const int4*)(dst + ebase);

    if (wave < 12) {
        // --- feat @ W for rows {wave, wave+12, ...}: each row is a fully
        // coalesced 1 KB load (64 lanes x float4). 33-34 rows per wave.
        const float4 w4 = ((const float4*)W)[lane];
        const float4* fb = (const float4*)feat + (size_t)nbase * 64;
        for (int r = wave; r < N_; r += 24) {      // unroll x2 by hand
            const int r2 = r + 12;
            float4 a0 = fb[(size_t)r * 64 + lane];
            float4 a1 = (r2 < N_) ? fb[(size_t)r2 * 64 + lane]
                                  : make_float4(0.f, 0.f, 0.f, 0.f);
            float d0 = a0.x*w4.x + a0.y*w4.y + a0.z*w4.z + a0.w*w4.w;
            float d1 = a1.x*w4.x + a1.y*w4.y + a1.z*w4.z + a1.w*w4.w;
            #pragma unroll
            for (int off = 32; off > 0; off >>= 1) {
                d0 += __shfl_down(d0, off, 64);
                d1 += __shfl_down(d1, off, 64);
            }
            if (lane == 0) {
                hl[r] = d0;
                if (r2 < N_) hl[r2] = d1;
            }
        }
    } else {
        // --- degree histograms: waves 12-15 (256 lanes), 12-13 int4 pairs each
        for (int i = tid - 768; i < EPG_ / 4; i += 256) {
            int4 s = s4[i]; int4 d = d4[i];
            atomicAdd(&ho[s.x - nbase], 1);
            atomicAdd(&ho[s.y - nbase], 1);
            atomicAdd(&ho[s.z - nbase], 1);
            atomicAdd(&ho[s.w - nbase], 1);
            atomicAdd(&hi[d.x - nbase], 1);
            atomicAdd(&hi[d.y - nbase], 1);
            atomicAdd(&hi[d.z - nbase], 1);
            atomicAdd(&hi[d.w - nbase], 1);
        }
    }
    __syncthreads();

    if (tid < N_)
        hl[tid] = hl[tid] * (1.0f / sqrtf(fmaxf((float)ho[tid], 1.0f)));
    __syncthreads();

    // --- normed scatter-sum (edges now L2-hot), all 16 waves
    for (int i = tid; i < EPG_ / 4; i += 1024) {
        int4 s = s4[i]; int4 d = d4[i];
        atomicAdd(&scl[d.x - nbase], hl[s.x - nbase]);
        atomicAdd(&scl[d.y - nbase], hl[s.y - nbase]);
        atomicAdd(&scl[d.z - nbase], hl[s.z - nbase]);
        atomicAdd(&scl[d.w - nbase], hl[s.w - nbase]);
    }
    __syncthreads();

    const float bb = bp[0];
    if (tid < N_) {
        float v = scl[tid] * (1.0f / sqrtf(fmaxf((float)hi[tid], 1.0f))) + bb;
        scl[tid] = v;
        score[nbase + tid] = v;
    }
    __syncthreads();

    // --- rank-select top-k (threads 0..N-1; LDS broadcast reads, no barriers)
    // rank_i = #{j : s_j > s_i or (s_j == s_i and j < i)}; selected iff < K,
    // list position == rank (== lax.top_k stable descending order).
    if (tid < N_) {
        const float v = scl[tid];
        int r = 0;
        for (int j = 0; j < N_; ++j) {
            float u = scl[j];
            r += (u > v) || (u == v && j < tid);
        }
        const int selb = (r < K_) ? 1 : 0;
        smask[tid] = selb;
        if (selb) {
            orow[nbase + tid] = g * K_ + r;                 // dis rows: [0, B*K)
            out[O_PERM + g * K_ + r] = (float)(nbase + tid);
        }
    }
    // Wave 15 (idle above) computes the per-graph softmax partial from scl.
    if (wave == 15) {
        float m = NEG_INF;
        for (int i = lane; i < N_; i += 64) m = fmaxf(m, scl[i]);
        #pragma unroll
        for (int o = 32; o > 0; o >>= 1) m = fmaxf(m, __shfl_xor(m, o, 64));
        float s = 0.0f;
        for (int i = lane; i < N_; i += 64) s += expf(scl[i] - m);
        #pragma unroll
        for (int o = 32; o > 0; o >>= 1) s += __shfl_xor(s, o, 64);
        if (lane == 0) { pm[g] = m; ps[g] = s; }
    }
    __syncthreads();

    // --- complement positions (ascending index among unselected)
    if (tid < N_ && !smask[tid]) {
        int pos = 0;
        for (int u = 0; u < tid; ++u) pos += (smask[u] == 0);
        orow[nbase + tid] = B_ * K_ + g * NKC_ + pos;       // com rows
        out[O_PCOM + g * NKC_ + pos] = (float)(nbase + tid);
    }

    // --- edge masks straight from LDS smask (edges still L2-hot); nt stores.
    float4* mdis = (float4*)(out + O_EDIS) + g * (EPG_ / 4);
    float4* mcom = (float4*)(out + O_ECOM) + g * (EPG_ / 4);
    for (int i = tid; i < EPG_ / 4; i += 1024) {
        int4 s = s4[i]; int4 d = d4[i];
        int a0 = smask[s.x - nbase], a1 = smask[s.y - nbase];
        int a2 = smask[s.z - nbase], a3 = smask[s.w - nbase];
        int b0 = smask[d.x - nbase], b1 = smask[d.y - nbase];
        int b2 = smask[d.z - nbase], b3 = smask[d.w - nbase];
        float4 vdis, vcom;
        vdis.x = (a0 & b0) ? 1.0f : 0.0f;  vcom.x = (a0 | b0) ? 0.0f : 1.0f;
        vdis.y = (a1 & b1) ? 1.0f : 0.0f;  vcom.y = (a1 | b1) ? 0.0f : 1.0f;
        vdis.z = (a2 & b2) ? 1.0f : 0.0f;  vcom.z = (a2 | b2) ? 0.0f : 1.0f;
        vdis.w = (a3 & b3) ? 1.0f : 0.0f;  vcom.w = (a3 | b3) ? 0.0f : 1.0f;
        nt_store4(&mdis[i], vdis);
        nt_store4(&mcom[i], vcom);
    }
}

// Combine per-graph (max,sumexp) into global (M,S)
__global__ __launch_bounds__(256) void k_soft_comb(const float* pm, const float* ps, float* red2) {
    __shared__ float rm[256], rs[256];
    int tid = threadIdx.x;
    float m = pm[tid];
    rm[tid] = m; __syncthreads();
    for (int o = 128; o > 0; o >>= 1) { if (tid < o) rm[tid] = fmaxf(rm[tid], rm[tid + o]); __syncthreads(); }
    float M = rm[0]; __syncthreads();
    rs[tid] = ps[tid] * expf(m - M); __syncthreads();
    for (int o = 128; o > 0; o >>= 1) { if (tid < o) rs[tid] += rs[tid + o]; __syncthreads(); }
    if (tid == 0) { red2[0] = M; red2[1] = rs[0]; }
}

// Gated gather with LINEAR feature reads: wave handles 4 consecutive nodes,
// writes each row to out + orow[n]*D (dis/com contiguous) with nt stores.
// feat's second read should largely hit L3 (nt stores keep it resident).
// Softmax output fused. Grid MUST be NT_/16 blocks.
__global__ __launch_bounds__(256) void k_gather(const float* __restrict__ feat,
                                                const float* __restrict__ score,
                                                const int* __restrict__ orow,
                                                const float* __restrict__ red2,
                                                float* __restrict__ out) {
    const int gw   = (blockIdx.x * 256 + threadIdx.x) >> 6;
    const int lane = threadIdx.x & 63;
    const int n0 = gw * 4;
    const float4* fb = (const float4*)feat;
    float4 v0 = fb[(size_t)(n0    ) * 64 + lane];
    float4 v1 = fb[(size_t)(n0 + 1) * 64 + lane];
    float4 v2 = fb[(size_t)(n0 + 2) * 64 + lane];
    float4 v3 = fb[(size_t)(n0 + 3) * 64 + lane];
    float s0 = score[n0], s1 = score[n0 + 1], s2 = score[n0 + 2], s3 = score[n0 + 3];
    int   r0 = orow[n0],  r1 = orow[n0 + 1],  r2 = orow[n0 + 2],  r3 = orow[n0 + 3];
    float t0 = tanhf(s0), t1 = tanhf(s1), t2 = tanhf(s2), t3 = tanhf(s3);
    v0.x *= t0; v0.y *= t0; v0.z *= t0; v0.w *= t0;
    v1.x *= t1; v1.y *= t1; v1.z *= t1; v1.w *= t1;
    v2.x *= t2; v2.y *= t2; v2.z *= t2; v2.w *= t2;
    v3.x *= t3; v3.y *= t3; v3.z *= t3; v3.w *= t3;
    nt_store4(((float4*)(out + (size_t)r0 * D_)) + lane, v0);
    nt_store4(((float4*)(out + (size_t)r1 * D_)) + lane, v1);
    nt_store4(((float4*)(out + (size_t)r2 * D_)) + lane, v2);
    nt_store4(((float4*)(out + (size_t)r3 * D_)) + lane, v3);
    if (lane == 0) {
        float M = red2[0], S = red2[1];
        out[O_SOFT + n0    ] = expf(s0 - M) / S;
        out[O_SOFT + n0 + 1] = expf(s1 - M) / S;
        out[O_SOFT + n0 + 2] = expf(s2 - M) / S;
        out[O_SOFT + n0 + 3] = expf(s3 - M) / S;
    }
}

extern "C" void kernel_launch(void* const* d_in, const int* in_sizes, int n_in,
                              void* d_out, int out_size, void* d_ws, size_t ws_size,
                              hipStream_t stream) {
    const float* feat = (const float*)d_in[0];
    const float* W    = (const float*)d_in[1];
    const float* bp   = (const float*)d_in[2];
    const int*   src  = (const int*)d_in[3];
    const int*   dst  = (const int*)d_in[4];
    float* out = (float*)d_out;

    char* ws = (char*)d_ws;
    float* score = (float*)(ws + 0);         // NT_ floats
    int*   orow  = (int*)  (ws + 409600);    // NT_ ints
    float* pm    = (float*)(ws + 819200);    // B_ floats
    float* ps    = (float*)(ws + 820224);    // B_ floats
    float* red2  = (float*)(ws + 821248);    // 2 floats

    k_graph    <<<B_,      1024, 0, stream>>>(feat, W, src, dst, bp,
                                              score, pm, ps, orow, out);    // 1 block / graph
    k_soft_comb<<<1,        256, 0, stream>>>(pm, ps, red2);
    k_gather   <<<NT_ / 16, 256, 0, stream>>>(feat, score, orow, red2, out);// 6400 blocks
}